// Round 3
// baseline (1068.345 us; speedup 1.0000x reference)
//
#include <hip/hip_runtime.h>
#include <stdint.h>

#define D_IN1 34   // msg MLP in: 12+12+8+1+1
#define H1    32
#define D_OUT1 24  // 8 (m_a) + 8 (m_b) + 8 (m_ab)
#define D_IN2 28   // upd MLP in: 8+8+12
#define H2    16
#define D_OUT2 8
#define CHN   12
#define CHE   8

__device__ __forceinline__ float clip100(float f) { return fminf(fmaxf(f, -100.f), 100.f); }

// ---- zero the degree + aggregate region of workspace ----
__global__ void k_zero(float* __restrict__ p, int n_words) {
    int i = blockIdx.x * blockDim.x + threadIdx.x;
    if (i < n_words) p[i] = 0.f;
}

// ---- degrees (f32), wave-uniform fast path for sorted sources ----
__global__ void k_degs(const int* __restrict__ src, const int* __restrict__ tgt,
                       float* __restrict__ outd, float* __restrict__ ind, int E) {
    int e = blockIdx.x * blockDim.x + threadIdx.x;
    bool v = e < E;
    int s = v ? src[e] : -1;
    int s0 = __shfl(s, 0);
    if (__all(v && s == s0)) {
        if ((threadIdx.x & 63) == 0) atomicAdd(&outd[s0], 64.f);
    } else if (v) {
        atomicAdd(&outd[s], 1.f);
    }
    if (v) atomicAdd(&ind[tgt[e]], 1.f);
}

// ---- per-edge message MLP + edge update + aggregation ----
__launch_bounds__(256)
__global__ void k_edge(const float* __restrict__ nodes, const float* __restrict__ edges,
                       const float* __restrict__ w1, const float* __restrict__ b1,
                       const float* __restrict__ w2, const float* __restrict__ b2,
                       const int* __restrict__ src, const int* __restrict__ tgt,
                       const float* __restrict__ outd, const float* __restrict__ ind,
                       float* __restrict__ agg_a, float* __restrict__ agg_b,
                       float* __restrict__ new_edges, int E, int N) {
    int e = blockIdx.x * blockDim.x + threadIdx.x;
    int b = blockIdx.y;
    bool v = e < E;

    int s = -1, t = -1;
    float m[D_OUT1];

    if (v) {
        s = src[e];
        t = tgt[e];

        float x[D_IN1];
        const float4* ns = (const float4*)(nodes + ((size_t)b * N + s) * CHN);
        const float4* nt = (const float4*)(nodes + ((size_t)b * N + t) * CHN);
#pragma unroll
        for (int i = 0; i < 3; ++i) {
            float4 a = ns[i];
            x[4*i] = a.x; x[4*i+1] = a.y; x[4*i+2] = a.z; x[4*i+3] = a.w;
        }
#pragma unroll
        for (int i = 0; i < 3; ++i) {
            float4 a = nt[i];
            x[12+4*i] = a.x; x[13+4*i] = a.y; x[14+4*i] = a.z; x[15+4*i] = a.w;
        }
        const float4* ep = (const float4*)(edges + ((size_t)b * E + e) * CHE);
        float4 e0 = ep[0], e1 = ep[1];
        x[24] = e0.x; x[25] = e0.y; x[26] = e0.z; x[27] = e0.w;
        x[28] = e1.x; x[29] = e1.y; x[30] = e1.z; x[31] = e1.w;
        x[32] = outd[s];
        x[33] = ind[t];

        // layer 1: 32 x 34 — wave-uniform weight indices -> s_load/SGPR operands
        float hb[H1];
#pragma unroll
        for (int h = 0; h < H1; ++h) {
            float a = b1[h];
#pragma unroll
            for (int i = 0; i < D_IN1; ++i) a = fmaf(w1[h * D_IN1 + i], x[i], a);
            hb[h] = fmaxf(a, 0.f);
        }
        // layer 2: 24 x 32
#pragma unroll
        for (int o = 0; o < D_OUT1; ++o) {
            float a = b2[o];
#pragma unroll
            for (int j = 0; j < H1; ++j) a = fmaf(w2[o * H1 + j], hb[j], a);
            m[o] = a;
        }

        // new_edges = clip(edges + m_ab)
        float4 o0, o1;
        o0.x = clip100(e0.x + m[16]); o0.y = clip100(e0.y + m[17]);
        o0.z = clip100(e0.z + m[18]); o0.w = clip100(e0.w + m[19]);
        o1.x = clip100(e1.x + m[20]); o1.y = clip100(e1.y + m[21]);
        o1.z = clip100(e1.z + m[22]); o1.w = clip100(e1.w + m[23]);
        float4* ow = (float4*)(new_edges + ((size_t)b * E + e) * CHE);
        ow[0] = o0; ow[1] = o1;

        // agg_b: targets distinct within a wave (tile pattern) -> direct atomics
        float* gb = agg_b + ((size_t)b * N + t) * 8;
#pragma unroll
        for (int c = 0; c < 8; ++c) atomicAdd(&gb[c], m[8 + c]);
    }

    // agg_a: sources in runs of 1040 -> usually wave-uniform; butterfly + 1 atomic/ch
    int s0 = __shfl(s, 0);
    bool fast = __all(v && s == s0);
    if (fast) {
        float* ga = agg_a + ((size_t)b * N + s0) * 8;
#pragma unroll
        for (int c = 0; c < 8; ++c) {
            float vv = m[c];
#pragma unroll
            for (int off = 32; off; off >>= 1) vv += __shfl_xor(vv, off);
            if ((threadIdx.x & 63) == 0) atomicAdd(&ga[c], vv);
        }
    } else if (v) {
        float* ga = agg_a + ((size_t)b * N + s) * 8;
#pragma unroll
        for (int c = 0; c < 8; ++c) atomicAdd(&ga[c], m[c]);
    }
}

// ---- per-node update MLP ----
__launch_bounds__(256)
__global__ void k_upd(const float* __restrict__ nodes,
                      const float* __restrict__ agg_a, const float* __restrict__ agg_b,
                      const float* __restrict__ outd, const float* __restrict__ ind,
                      const float* __restrict__ u1, const float* __restrict__ ub1,
                      const float* __restrict__ u2, const float* __restrict__ ub2,
                      float* __restrict__ new_nodes, int N, int total) {
    int i = blockIdx.x * blockDim.x + threadIdx.x;
    if (i >= total) return;
    int n = i % N;

    float od = fmaxf(outd[n], 1.f);
    float dg = fmaxf(ind[n], 1.f);
    float rod = 1.f / od, rdg = 1.f / dg;

    float ux[D_IN2];
    const float4* ga = (const float4*)(agg_a + (size_t)i * 8);
    const float4* gb = (const float4*)(agg_b + (size_t)i * 8);
    float4 a0 = ga[0], a1 = ga[1], b0 = gb[0], b1v = gb[1];
    ux[0] = a0.x * rod; ux[1] = a0.y * rod; ux[2] = a0.z * rod; ux[3] = a0.w * rod;
    ux[4] = a1.x * rod; ux[5] = a1.y * rod; ux[6] = a1.z * rod; ux[7] = a1.w * rod;
    ux[8]  = b0.x * rdg; ux[9]  = b0.y * rdg; ux[10] = b0.z * rdg; ux[11] = b0.w * rdg;
    ux[12] = b1v.x * rdg; ux[13] = b1v.y * rdg; ux[14] = b1v.z * rdg; ux[15] = b1v.w * rdg;

    const float4* np4 = (const float4*)(nodes + (size_t)i * CHN);
    float4 n0 = np4[0], n1 = np4[1], n2 = np4[2];
    ux[16] = n0.x; ux[17] = n0.y; ux[18] = n0.z; ux[19] = n0.w;
    ux[20] = n1.x; ux[21] = n1.y; ux[22] = n1.z; ux[23] = n1.w;
    ux[24] = n2.x; ux[25] = n2.y; ux[26] = n2.z; ux[27] = n2.w;

    float hb[H2];
#pragma unroll
    for (int h = 0; h < H2; ++h) {
        float a = ub1[h];
#pragma unroll
        for (int k = 0; k < D_IN2; ++k) a = fmaf(u1[h * D_IN2 + k], ux[k], a);
        hb[h] = fmaxf(a, 0.f);
    }
    float up[D_OUT2];
#pragma unroll
    for (int o = 0; o < D_OUT2; ++o) {
        float a = ub2[o];
#pragma unroll
        for (int k = 0; k < H2; ++k) a = fmaf(u2[o * H2 + k], hb[k], a);
        up[o] = clip100(ux[16 + o] + a);
    }
    float4* onp = (float4*)(new_nodes + (size_t)i * CHN);
    onp[0] = make_float4(up[0], up[1], up[2], up[3]);
    onp[1] = make_float4(up[4], up[5], up[6], up[7]);
    onp[2] = n2;   // const channels 8..11 pass through
}

extern "C" void kernel_launch(void* const* d_in, const int* in_sizes, int n_in,
                              void* d_out, int out_size, void* d_ws, size_t ws_size,
                              hipStream_t stream) {
    const float* nodes = (const float*)d_in[0];
    const float* edges = (const float*)d_in[1];
    const float* mw1   = (const float*)d_in[2];
    const float* mb1   = (const float*)d_in[3];
    const float* mw2   = (const float*)d_in[4];
    const float* mb2   = (const float*)d_in[5];
    const float* uw1   = (const float*)d_in[6];
    const float* ubb1  = (const float*)d_in[7];
    const float* uw2   = (const float*)d_in[8];
    const float* ubb2  = (const float*)d_in[9];
    const int* src     = (const int*)d_in[10];
    const int* tgt     = (const int*)d_in[11];

    int E = in_sizes[10];
    int B = in_sizes[1] / (E * 8);
    int N = in_sizes[0] / (B * 12);

    // workspace: [outd(N) | ind(N) | agg_a(B*N*8) | agg_b(B*N*8)] f32
    float* outd  = (float*)d_ws;
    float* ind   = outd + N;
    float* agg_a = ind + N;
    float* agg_b = agg_a + (size_t)B * N * 8;

    int zero_words = 2 * N + B * N * 16;
    k_zero<<<(zero_words + 255) / 256, 256, 0, stream>>>((float*)d_ws, zero_words);
    k_degs<<<(E + 255) / 256, 256, 0, stream>>>(src, tgt, outd, ind, E);

    float* out_nodes = (float*)d_out;
    float* out_edges = out_nodes + (size_t)B * N * 12;

    dim3 ge((E + 255) / 256, B);
    k_edge<<<ge, 256, 0, stream>>>(nodes, edges, mw1, mb1, mw2, mb2, src, tgt,
                                   outd, ind, agg_a, agg_b, out_edges, E, N);
    k_upd<<<(B * N + 255) / 256, 256, 0, stream>>>(nodes, agg_a, agg_b, outd, ind,
                                                   uw1, ubb1, uw2, ubb2,
                                                   out_nodes, N, B * N);
}

// Round 4
// 548.017 us; speedup vs baseline: 1.9495x; 1.9495x over previous
//
#include <hip/hip_runtime.h>
#include <stdint.h>

#define D_IN1 34   // msg MLP in: 12+12+8+1+1
#define H1    32
#define D_OUT1 24  // 8 (m_a) + 8 (m_b) + 8 (m_ab)
#define D_IN2 28   // upd MLP in: 8+8+12
#define H2    16
#define D_OUT2 8
#define CHN   12
#define CHE   8

__device__ __forceinline__ float clip100(float f) { return fminf(fmaxf(f, -100.f), 100.f); }

// ---- zero degree ints + agg_a ----
__global__ void k_zero(int* __restrict__ p, int n_words) {
    int i = blockIdx.x * blockDim.x + threadIdx.x;
    if (i < n_words) p[i] = 0;
}

// ---- degrees via LDS histogram (wave-uniform fast path for sorted sources) ----
__global__ void k_degs(const int* __restrict__ src, const int* __restrict__ tgt,
                       int* __restrict__ outd, int* __restrict__ ind, int E, int N) {
    extern __shared__ int hist[];          // [2*N]
    int* ho = hist;
    int* hi = hist + N;
    for (int k = threadIdx.x; k < 2 * N; k += blockDim.x) hist[k] = 0;
    __syncthreads();
    for (int e = blockIdx.x * blockDim.x + threadIdx.x; e < E;
         e += gridDim.x * blockDim.x) {
        int s = src[e];
        int t = tgt[e];
        int s0 = __shfl(s, 0);             // lane0 always active (smallest e in wave)
        unsigned long long act = __ballot(1);
        if (__all(s == s0)) {
            if ((threadIdx.x & 63) == 0) atomicAdd(&ho[s0], (int)__popcll(act));
        } else {
            atomicAdd(&ho[s], 1);
        }
        atomicAdd(&hi[t], 1);
    }
    __syncthreads();
    for (int k = threadIdx.x; k < N; k += blockDim.x) {
        int a = ho[k], b = hi[k];
        if (a) atomicAdd(&outd[k], a);
        if (b) atomicAdd(&ind[k], b);
    }
}

// ---- per-edge MLP + edge update; agg_b into LDS, flushed once per block ----
__launch_bounds__(256)
__global__ void k_edge(const float* __restrict__ nodes, const float* __restrict__ edges,
                       const float* __restrict__ w1, const float* __restrict__ b1,
                       const float* __restrict__ w2, const float* __restrict__ b2,
                       const int* __restrict__ src, const int* __restrict__ tgt,
                       const int* __restrict__ outd, const int* __restrict__ ind,
                       float* __restrict__ agg_a, float* __restrict__ partials,
                       float* __restrict__ new_edges, int E, int N, int nblk) {
    extern __shared__ float aggB[];        // [8][N]
    int blk = blockIdx.x, b = blockIdx.y;
    for (int k = threadIdx.x; k < 8 * N; k += 256) aggB[k] = 0.f;
    __syncthreads();

    int chunk = (E + nblk - 1) / nblk;
    int start = blk * chunk;
    int end   = min(E, start + chunk);

    for (int base = start; base < end; base += 256) {
        int e = base + threadIdx.x;
        bool v = e < end;

        int s = -1, t = -1;
        float m[D_OUT1];

        if (v) {
            s = src[e];
            t = tgt[e];

            float x[D_IN1];
            const float4* ns = (const float4*)(nodes + ((size_t)b * N + s) * CHN);
            const float4* nt = (const float4*)(nodes + ((size_t)b * N + t) * CHN);
#pragma unroll
            for (int i = 0; i < 3; ++i) {
                float4 a = ns[i];
                x[4*i] = a.x; x[4*i+1] = a.y; x[4*i+2] = a.z; x[4*i+3] = a.w;
            }
#pragma unroll
            for (int i = 0; i < 3; ++i) {
                float4 a = nt[i];
                x[12+4*i] = a.x; x[13+4*i] = a.y; x[14+4*i] = a.z; x[15+4*i] = a.w;
            }
            const float4* ep = (const float4*)(edges + ((size_t)b * E + e) * CHE);
            float4 e0 = ep[0], e1 = ep[1];
            x[24] = e0.x; x[25] = e0.y; x[26] = e0.z; x[27] = e0.w;
            x[28] = e1.x; x[29] = e1.y; x[30] = e1.z; x[31] = e1.w;
            x[32] = (float)outd[s];
            x[33] = (float)ind[t];

            // layer 1: 32 x 34 — wave-uniform weight indices -> s_load/SGPR operands
            float hb[H1];
#pragma unroll
            for (int h = 0; h < H1; ++h) {
                float a = b1[h];
#pragma unroll
                for (int i = 0; i < D_IN1; ++i) a = fmaf(w1[h * D_IN1 + i], x[i], a);
                hb[h] = fmaxf(a, 0.f);
            }
            // layer 2: 24 x 32
#pragma unroll
            for (int o = 0; o < D_OUT1; ++o) {
                float a = b2[o];
#pragma unroll
                for (int j = 0; j < H1; ++j) a = fmaf(w2[o * H1 + j], hb[j], a);
                m[o] = a;
            }

            // new_edges = clip(edges + m_ab)
            float4 o0, o1;
            o0.x = clip100(e0.x + m[16]); o0.y = clip100(e0.y + m[17]);
            o0.z = clip100(e0.z + m[18]); o0.w = clip100(e0.w + m[19]);
            o1.x = clip100(e1.x + m[20]); o1.y = clip100(e1.y + m[21]);
            o1.z = clip100(e1.z + m[22]); o1.w = clip100(e1.w + m[23]);
            float4* ow = (float4*)(new_edges + ((size_t)b * E + e) * CHE);
            ow[0] = o0; ow[1] = o1;

            // agg_b into LDS: [c][t] layout -> consecutive lanes hit consecutive words
#pragma unroll
            for (int c = 0; c < 8; ++c) atomicAdd(&aggB[c * N + t], m[8 + c]);
        }

        // agg_a: sources in long runs -> usually wave-uniform; butterfly + 1 atomic/ch
        int s0 = __shfl(s, 0);
        bool fast = __all(v && s == s0);
        if (fast) {
            float* ga = agg_a + ((size_t)b * N + s0) * 8;
#pragma unroll
            for (int c = 0; c < 8; ++c) {
                float vv = m[c];
#pragma unroll
                for (int off = 32; off; off >>= 1) vv += __shfl_xor(vv, off);
                if ((threadIdx.x & 63) == 0) atomicAdd(&ga[c], vv);
            }
        } else if (v) {
            float* ga = agg_a + ((size_t)b * N + s) * 8;
#pragma unroll
            for (int c = 0; c < 8; ++c) atomicAdd(&ga[c], m[c]);
        }
    }

    __syncthreads();
    float* P = partials + ((size_t)b * nblk + blk) * 8 * N;
    for (int k = threadIdx.x; k < 8 * N; k += 256) P[k] = aggB[k];
}

// ---- sum per-block partials into agg_b [b][t][c] ----
__global__ void k_aggb(const float* __restrict__ partials, float* __restrict__ agg_b,
                       int nblk, int N, int total /* B*8*N */) {
    int id = blockIdx.x * blockDim.x + threadIdx.x;
    if (id >= total) return;
    int b = id / (8 * N);
    int r = id % (8 * N);
    int c = r / N;
    int t = r % N;
    float sum = 0.f;
    for (int p = 0; p < nblk; ++p)
        sum += partials[((size_t)b * nblk + p) * 8 * N + r];
    agg_b[((size_t)b * N + t) * 8 + c] = sum;
}

// ---- per-node update MLP ----
__launch_bounds__(256)
__global__ void k_upd(const float* __restrict__ nodes,
                      const float* __restrict__ agg_a, const float* __restrict__ agg_b,
                      const int* __restrict__ outd, const int* __restrict__ ind,
                      const float* __restrict__ u1, const float* __restrict__ ub1,
                      const float* __restrict__ u2, const float* __restrict__ ub2,
                      float* __restrict__ new_nodes, int N, int total) {
    int i = blockIdx.x * blockDim.x + threadIdx.x;
    if (i >= total) return;
    int n = i % N;

    float rod = 1.f / fmaxf((float)outd[n], 1.f);
    float rdg = 1.f / fmaxf((float)ind[n], 1.f);

    float ux[D_IN2];
    const float4* ga = (const float4*)(agg_a + (size_t)i * 8);
    const float4* gb = (const float4*)(agg_b + (size_t)i * 8);
    float4 a0 = ga[0], a1 = ga[1], b0 = gb[0], b1v = gb[1];
    ux[0] = a0.x * rod; ux[1] = a0.y * rod; ux[2] = a0.z * rod; ux[3] = a0.w * rod;
    ux[4] = a1.x * rod; ux[5] = a1.y * rod; ux[6] = a1.z * rod; ux[7] = a1.w * rod;
    ux[8]  = b0.x * rdg; ux[9]  = b0.y * rdg; ux[10] = b0.z * rdg; ux[11] = b0.w * rdg;
    ux[12] = b1v.x * rdg; ux[13] = b1v.y * rdg; ux[14] = b1v.z * rdg; ux[15] = b1v.w * rdg;

    const float4* np4 = (const float4*)(nodes + (size_t)i * CHN);
    float4 n0 = np4[0], n1 = np4[1], n2 = np4[2];
    ux[16] = n0.x; ux[17] = n0.y; ux[18] = n0.z; ux[19] = n0.w;
    ux[20] = n1.x; ux[21] = n1.y; ux[22] = n1.z; ux[23] = n1.w;
    ux[24] = n2.x; ux[25] = n2.y; ux[26] = n2.z; ux[27] = n2.w;

    float hb[H2];
#pragma unroll
    for (int h = 0; h < H2; ++h) {
        float a = ub1[h];
#pragma unroll
        for (int k = 0; k < D_IN2; ++k) a = fmaf(u1[h * D_IN2 + k], ux[k], a);
        hb[h] = fmaxf(a, 0.f);
    }
    float up[D_OUT2];
#pragma unroll
    for (int o = 0; o < D_OUT2; ++o) {
        float a = ub2[o];
#pragma unroll
        for (int k = 0; k < H2; ++k) a = fmaf(u2[o * H2 + k], hb[k], a);
        up[o] = clip100(ux[16 + o] + a);
    }
    float4* onp = (float4*)(new_nodes + (size_t)i * CHN);
    onp[0] = make_float4(up[0], up[1], up[2], up[3]);
    onp[1] = make_float4(up[4], up[5], up[6], up[7]);
    onp[2] = n2;   // const channels 8..11 pass through
}

extern "C" void kernel_launch(void* const* d_in, const int* in_sizes, int n_in,
                              void* d_out, int out_size, void* d_ws, size_t ws_size,
                              hipStream_t stream) {
    const float* nodes = (const float*)d_in[0];
    const float* edges = (const float*)d_in[1];
    const float* mw1   = (const float*)d_in[2];
    const float* mb1   = (const float*)d_in[3];
    const float* mw2   = (const float*)d_in[4];
    const float* mb2   = (const float*)d_in[5];
    const float* uw1   = (const float*)d_in[6];
    const float* ubb1  = (const float*)d_in[7];
    const float* uw2   = (const float*)d_in[8];
    const float* ubb2  = (const float*)d_in[9];
    const int* src     = (const int*)d_in[10];
    const int* tgt     = (const int*)d_in[11];

    int E = in_sizes[10];
    int B = in_sizes[1] / (E * 8);
    int N = in_sizes[0] / (B * 12);

    // workspace layout (64B-aligned regions):
    // [outd(N i32) | ind(N i32) | agg_a(B*N*8 f32) | agg_b(B*N*8 f32) | partials]
    size_t off = 0;
    int* outd = (int*)((char*)d_ws + off);                 off += (size_t)N * 4;
    off = (off + 63) & ~(size_t)63;
    int* ind  = (int*)((char*)d_ws + off);                 off += (size_t)N * 4;
    off = (off + 63) & ~(size_t)63;
    float* agg_a = (float*)((char*)d_ws + off);            off += (size_t)B * N * 8 * 4;
    off = (off + 63) & ~(size_t)63;
    float* agg_b = (float*)((char*)d_ws + off);            off += (size_t)B * N * 8 * 4;
    off = (off + 63) & ~(size_t)63;
    float* partials = (float*)((char*)d_ws + off);

    // adaptive partial count: one [8][N] f32 slab per (batch, block)
    size_t per_blk = (size_t)B * 8 * N * sizeof(float);
    size_t avail = (ws_size > off) ? (ws_size - off) : 0;
    int nblk = (int)(avail / per_blk);
    if (nblk > 256) nblk = 256;
    if (nblk < 8)   nblk = 8;       // fallback; needs ~566KB min

    // zero degrees + agg_a (agg_b and partials are fully overwritten)
    k_zero<<<((2 * N + 255) / 256), 256, 0, stream>>>(outd, N);
    k_zero<<<((2 * N + 255) / 256), 256, 0, stream>>>(ind, N);
    {
        int zw = B * N * 8;
        k_zero<<<((zw + 255) / 256), 256, 0, stream>>>((int*)agg_a, zw);
    }

    k_degs<<<64, 256, 2 * N * sizeof(int), stream>>>(src, tgt, outd, ind, E, N);

    float* out_nodes = (float*)d_out;
    float* out_edges = out_nodes + (size_t)B * N * 12;

    dim3 ge(nblk, B);
    k_edge<<<ge, 256, 8 * N * sizeof(float), stream>>>(
        nodes, edges, mw1, mb1, mw2, mb2, src, tgt, outd, ind,
        agg_a, partials, out_edges, E, N, nblk);

    int totb = B * 8 * N;
    k_aggb<<<(totb + 255) / 256, 256, 0, stream>>>(partials, agg_b, nblk, N, totb);

    k_upd<<<(B * N + 255) / 256, 256, 0, stream>>>(nodes, agg_a, agg_b, outd, ind,
                                                   uw1, ubb1, uw2, ubb2,
                                                   out_nodes, N, B * N);
}